// Round 10
// baseline (228.286 us; speedup 1.0000x reference)
//
#include <hip/hip_runtime.h>

typedef _Float16 h8 __attribute__((ext_vector_type(8)));
typedef float    f4 __attribute__((ext_vector_type(4)));
typedef unsigned int u4 __attribute__((ext_vector_type(4)));

#define IMG_N 8
#define IMG_H 512
#define IMG_W 512
#define P_CNT 256
#define PSFN  64
#define SENS  1024

// fp16 tiles, parity-planar (same plane offsets as R9, now in halves):
// (0,0)@0 4096, (0,1)@4096 4096, (1,0)@8192 4032, (1,1)@12224 4032
#define TILE_HALVES 16256
#define TILES_BYTES ((size_t)IMG_N * P_CNT * TILE_HALVES * 2)   // 66,584,576

// Kfrag[p][cls][g][w]: h8 entry w holds halves {K_cls[e = w+j-32][g]}_{j=0..7},
// 16B-aligned by construction (alignment via duplication in global memory).
// w = t0 = 8q - m + (U0-16ut) + 32 in [0,89) -> 90 entries (R9-verified algebra).
#define KW     90
#define KFRAG_PER_P (4 * 33 * KW)    // 11880 entries (190080 B per region)

// BT[97 cols][40 r] fp16, col = c+32, zero-padded outside c in [0,32).
#define BT_COLS   97
#define BT_HALVES (BT_COLS * 40)     // 3880

// ---------------- prep: build Kfrag fragment table in d_ws ----------------
__global__ __launch_bounds__(256) void svconv_prep(
    const float* __restrict__ psf, u4* __restrict__ kfrag)
{
    __shared__ float ps[PSFN * PSFN];      // 16384 B
    __shared__ float Kc[4 * 33 * 33];      // 17424 B  (Kc[cls][e][g], zero if invalid)
    const int p = blockIdx.x, tid = threadIdx.x;

    const float4* pp = (const float4*)(psf + (size_t)p * PSFN * PSFN);
    float4* pd = (float4*)ps;
    for (int i = tid; i < PSFN * PSFN / 4; i += 256) pd[i] = pp[i];
    __syncthreads();

    // K_cls[e][g] = Wp[a=2e-1+pi][b=2g-1+pj], Wp = 2x2-aggregated psf
    for (int idx = tid; idx < 4 * 33 * 33; idx += 256) {
        const int g = idx % 33, e = (idx / 33) % 33, cls = idx / 1089;
        const int pi = cls >> 1, pj = cls & 1;
        const int E = pi ? 32 : 33;
        float sv = 0.f;
        if (e < E) {
            const int a = 2 * e - 1 + pi, b = 2 * g - 1 + pj;
            #pragma unroll
            for (int du = 0; du < 2; ++du) {
                const int x = a + du;
                if ((unsigned)x < 64u) {
                    #pragma unroll
                    for (int dv = 0; dv < 2; ++dv) {
                        const int y = b + dv;
                        if ((unsigned)y < 64u) sv += ps[x * 64 + y];
                    }
                }
            }
        }
        Kc[idx] = sv;
    }
    __syncthreads();

    u4* kout = kfrag + (size_t)p * KFRAG_PER_P;
    for (int idx = tid; idx < KFRAG_PER_P; idx += 256) {
        const int w = idx % KW;
        const int g = (idx / KW) % 33;
        const int cls = idx / (KW * 33);
        h8 hv;
        #pragma unroll
        for (int j = 0; j < 8; ++j) {
            const int e = w + j - 32;
            const float v = ((unsigned)e < 33u) ? Kc[cls * 1089 + e * 33 + g] : 0.f;
            hv[j] = (_Float16)v;
        }
        kout[idx] = __builtin_bit_cast(u4, hv);
    }
}

// ---------------- main: MFMA with global A-fragments, LDS B only ----------
__global__ __launch_bounds__(256, 4) void svconv_main(
    const float* __restrict__ imgs, const u4* __restrict__ kfrag,
    _Float16* __restrict__ tiles)
{
    __shared__ __align__(16) _Float16 BT[BT_HALVES];   // 7760 B only

    const int bid = blockIdx.x;
    const int n = bid >> 8, p = bid & 255;
    const int bh = p & 15, bw = p >> 4;
    const int tid = threadIdx.x;
    const int wv = tid >> 6, lane = tid & 63;
    const int m = lane & 15, q = lane >> 4;

    for (int i = tid; i < BT_HALVES; i += 256) BT[i] = (_Float16)0.f;
    __syncthreads();
    {
        const int r0 = tid >> 5, c = tid & 31;
        const float* src = imgs + ((size_t)n * IMG_H + bh * 32) * IMG_W + bw * 32;
        for (int r = r0; r < 32; r += 8)
            BT[(c + 32) * 40 + r] = (_Float16)src[r * IMG_W + c];
    }
    __syncthreads();

    const int cls = wv, pi = cls >> 1, pj = cls & 1;
    const int U0 = pi ? 31 : 32;
    const char* btc = (const char*)BT + pj * 80;   // pj: c = v+g-32+pj (R9 fix)

    int boff[4];
    #pragma unroll
    for (int vt = 0; vt < 4; ++vt) boff[vt] = (16 * vt + m) * 80 + q * 16;

    const char* ka[4];
    {
        const char* base = (const char*)(kfrag + (size_t)p * KFRAG_PER_P
                                         + cls * 33 * KW);
        #pragma unroll
        for (int ut = 0; ut < 4; ++ut) {
            const int t0 = 8 * q - m + (U0 - 16 * ut) + 32;   // in [0,88]
            ka[ut] = base + t0 * 16;
        }
    }

    f4 acc[4][4];
    #pragma unroll
    for (int ut = 0; ut < 4; ++ut)
        #pragma unroll
        for (int vt = 0; vt < 4; ++vt) acc[ut][vt] = (f4){0.f, 0.f, 0.f, 0.f};

    #pragma unroll 3
    for (int g = 0; g < 33; ++g) {
        h8 A[4];
        #pragma unroll
        for (int ut = 0; ut < 4; ++ut)
            A[ut] = __builtin_bit_cast(h8, *(const u4*)(ka[ut] + g * (KW * 16)));
        h8 B[4];
        #pragma unroll
        for (int vt = 0; vt < 4; ++vt)
            B[vt] = *(const h8*)(btc + boff[vt] + g * 80);
        #pragma unroll
        for (int ut = 0; ut < 4; ++ut)
            #pragma unroll
            for (int vt = 0; vt < 4; ++vt)
                acc[ut][vt] = __builtin_amdgcn_mfma_f32_16x16x32_f16(
                    A[ut], B[vt], acc[ut][vt], 0, 0, 0);
    }

    // epilogue: C/D col=lane&15 (v), row=quad*4+reg (u); fp16 planar tile
    _Float16* tile = tiles + (size_t)(n * P_CNT + p) * TILE_HALVES;
    const int plane = pi ? (8192 + pj * 4032) : (pj * 4096);
    #pragma unroll
    for (int ut = 0; ut < 4; ++ut) {
        #pragma unroll
        for (int reg = 0; reg < 4; ++reg) {
            const int u = 16 * ut + 4 * q + reg;
            if (pi == 0 || u < 63) {                 // pi=1 u=63 -> i=127 discard
                _Float16* rp = tile + plane + u * 64 + m;
                #pragma unroll
                for (int vt = 0; vt < 4; ++vt)
                    rp[16 * vt] = (_Float16)acc[ut][vt][reg];
            }
        }
    }
}

// ---------------- gather: every pixel written unconditionally --------------
__global__ __launch_bounds__(256) void svconv_gather(
    const _Float16* __restrict__ ws, float* __restrict__ out)
{
    const int b = blockIdx.x;
    const int n = b >> 10, x = b & 1023;
    int bhlo = (x + 288) / 48 - 10; if (bhlo < 0) bhlo = 0;
    int bhhi = (x < 113) ? -1 : ((x - 113) / 48);
    if (bhhi > 15) bhhi = 15;
    const _Float16* wsn = ws + (size_t)n * P_CNT * TILE_HALVES;
    float* outrow = out + ((size_t)n << 20) + (size_t)x * SENS;

    for (int yb = 0; yb < 4; ++yb) {
        const int y = yb * 256 + threadIdx.x;
        int bwlo = (y + 288) / 48 - 10; if (bwlo < 0) bwlo = 0;
        int bwhi = (y < 113) ? -1 : ((y - 113) / 48);
        if (bwhi > 15) bwhi = 15;
        float s = 0.0f;
        for (int bhh = bhlo; bhh <= bhhi; ++bhh) {
            const int ti = x - 113 - 48 * bhh;          // 0..126
            const int pi = ti & 1, uu = ti >> 1;
            for (int bww = bwlo; bww <= bwhi; ++bww) {
                const int tj = y - 113 - 48 * bww;      // 0..126
                const int pj = tj & 1, vv = tj >> 1;
                const int base = pi ? (8192 + pj * 4032) : (pj * 4096);
                s += (float)wsn[(size_t)(bww * 16 + bhh) * TILE_HALVES
                                + base + uu * 64 + vv];
            }
        }
        outrow[y] = s;   // uncovered pixels get exact 0
    }
}

extern "C" void kernel_launch(void* const* d_in, const int* in_sizes, int n_in,
                              void* d_out, int out_size, void* d_ws, size_t ws_size,
                              hipStream_t stream) {
    const float* imgs = (const float*)d_in[0];
    const float* psf  = (const float*)d_in[1];
    float* out = (float*)d_out;
    _Float16* tiles = (_Float16*)d_ws;                          // 66.6 MB
    u4* kfrag = (u4*)((char*)d_ws + TILES_BYTES);               // 48.7 MB (total 115 MB)

    svconv_prep<<<dim3(P_CNT), dim3(256), 0, stream>>>(psf, kfrag);
    svconv_main<<<dim3(IMG_N * P_CNT), dim3(256), 0, stream>>>(imgs, kfrag, tiles);
    svconv_gather<<<dim3(IMG_N * SENS), dim3(256), 0, stream>>>(tiles, out);
}